// Round 1
// 676.529 us; speedup vs baseline: 1.3998x; 1.3998x over previous
//
#include <hip/hip_runtime.h>
#include <math.h>

#define B_ 8
#define P_ 8192
#define N_ 65536
#define K_ 16
#define EPS_ 1e-5f
#define NBK 1024                 // x-buckets per batch
#define BSCALE 20.48f            // NBK / 50.0

// ============================ binning (R5, proven) =========================
__global__ __launch_bounds__(256) void init_bins(int* counts, int* cursors,
                                                 int* xminI, int* xmaxI) {
    int i = blockIdx.x * 256 + threadIdx.x;   // 8192 entries
    counts[i] = 0; cursors[i] = 0;
    xminI[i] = 0x7F7FFFFF;                    // non-neg floats: int order == float order
    xmaxI[i] = 0x80000000;
}

__device__ __forceinline__ int bucket_of(float x) {
    int b = (int)(x * BSCALE);
    return b > (NBK - 1) ? (NBK - 1) : (b < 0 ? 0 : b);
}

__global__ __launch_bounds__(256) void count_kernel(const float* __restrict__ vc,
                                                    int* counts, int* xminI, int* xmaxI) {
    int q = blockIdx.x * 256 + threadIdx.x;
    float4 p = ((const float4*)vc)[q];        // [batch, x, y, z]
    int b = q >> 13;
    int bk = bucket_of(p.y);
    int e = b * NBK + bk;
    atomicAdd(&counts[e], 1);
    int xb = __float_as_int(p.y);
    atomicMin(&xminI[e], xb);
    atomicMax(&xmaxI[e], xb);
}

__global__ __launch_bounds__(1024) void scan_kernel(const int* __restrict__ counts,
                                                    const int* __restrict__ xminI,
                                                    const int* __restrict__ xmaxI,
                                                    int* off, float* xlub, float* xglb) {
    __shared__ int   smi[NBK];
    __shared__ float smf[NBK];
    int b = blockIdx.x, t = threadIdx.x;
    int e = b * NBK + t;

    int c = counts[e];
    smi[t] = c; __syncthreads();
    for (int s = 1; s < NBK; s <<= 1) {
        int u = smi[t]; int v = (t >= s) ? smi[t - s] : 0;
        __syncthreads(); smi[t] = u + v; __syncthreads();
    }
    off[b * (NBK + 1) + t] = smi[t] - c;
    if (t == NBK - 1) off[b * (NBK + 1) + NBK] = smi[t];

    float mx = c ? __int_as_float(xmaxI[e]) : -1e30f;
    smf[t] = mx; __syncthreads();
    for (int s = 1; s < NBK; s <<= 1) {
        float u = smf[t]; float v = (t >= s) ? smf[t - s] : -1e30f;
        __syncthreads(); smf[t] = fmaxf(u, v); __syncthreads();
    }
    xlub[e] = smf[t];
    __syncthreads();

    int r = NBK - 1 - t;
    int cr_ = counts[b * NBK + r];
    float mn = cr_ ? __int_as_float(xminI[b * NBK + r]) : 1e30f;
    smf[t] = mn; __syncthreads();
    for (int s = 1; s < NBK; s <<= 1) {
        float u = smf[t]; float v = (t >= s) ? smf[t - s] : 1e30f;
        __syncthreads(); smf[t] = fminf(u, v); __syncthreads();
    }
    xglb[b * NBK + r] = smf[t];
}

__global__ __launch_bounds__(256) void scatter_kernel(const float* __restrict__ vc,
                                                      const int* __restrict__ off,
                                                      int* cursors, float4* pos4s) {
    int q = blockIdx.x * 256 + threadIdx.x;
    float4 p = ((const float4*)vc)[q];
    int b = q >> 13;
    int bk = bucket_of(p.y);
    int slot = off[b * (NBK + 1) + bk] + atomicAdd(&cursors[b * NBK + bk], 1);
    pos4s[(b << 13) + slot] = make_float4(p.y, p.z, p.w, __int_as_float(q));
}

// ============================ knn4: 4 threads per query ====================
// Occupancy fix: the old 1-thread-per-query version was pinned at grid=256
// blocks (1 block/CU, 4 waves/CU, 10% occupancy, 26% VALUBusy -> pure
// latency-bound). Now a quad of adjacent lanes shares one query:
//   - 64 queries/block, grid = 1024 -> 4 blocks/CU = 16 waves/CU.
//   - each sub-thread scans a stride-4 quarter of each 256-tile, keeping its
//     own sorted top-16 distance list.
//   - the pruning bound stays EXACT: a register bitonic top-k merge across
//     the quad (m[i]=min(A[i],shfl(B[15-i])) is the 16-smallest of two sorted
//     lists) yields the union's true 16th-smallest at every expansion step,
//     so no extra tiles are scanned vs the single-thread version.
//   - pass 2 collects (d, idx) hits per thread in LDS; tie-dropping and the
//     final write are distributed across the quad (order is a permutation of
//     the old one; downstream is permutation-invariant in k).
__global__ __launch_bounds__(256, 4) void knn3_kernel(const float4* __restrict__ pos4s,
                                                   const float* __restrict__ xlub,
                                                   const float* __restrict__ xglb,
                                                   unsigned short* __restrict__ idx_out,
                                                   float* __restrict__ d2_out) {
    const int tid   = threadIdx.x;
    const int sub   = tid & 3;                     // position within quad
    const int bb    = blockIdx.x >> 7;             // batch (128 blocks/batch)
    const int bbase = bb << 13;
    const int wq    = blockIdx.x & 127;            // 64-query group within batch
    const int home0 = bbase + ((wq >> 2) << 8);    // aligned 256-tile containing group
    const int qslot = bbase + (wq << 6) + (tid >> 2);
    const float4 me = pos4s[qslot];
    const float qx = me.x, qy = me.y, qz = me.z;
    const int q = __float_as_int(me.w);
    const float* xl = xlub + (bb << 10);
    const float* xg = xglb + (bb << 10);

    __shared__ __align__(16) float4 tile[256];       // 4 KB
    __shared__ float          hbD[256 * 19];         // 19 KB hit distances
    __shared__ unsigned short hbI[256 * 19];         // 9.5 KB hit indices
    __shared__ int sflags[2];

    float bd[K_];
#pragma unroll
    for (int t = 0; t < K_; ++t) bd[t] = __builtin_huge_valf();
    float bd15 = __builtin_huge_valf();              // own 16th (quarter-stream)
    float sbd  = __builtin_huge_valf();              // quad-union exact 16th

    // exact 16th-smallest of the union of the quad's 4 sorted 16-lists.
    // level 1 (lane^1): m = 16-smallest of pair (bitonic), 4-stage cleanup sort;
    // level 2 (lane^2): tau = max of elementwise min vs partner-pair reversed.
    auto QUAD16 = [&]() -> float {
        float m[16];
#pragma unroll
        for (int i = 0; i < 16; ++i)
            m[i] = fminf(bd[i], __shfl_xor(bd[15 - i], 1, 64));
#pragma unroll
        for (int dd = 8; dd >= 1; dd >>= 1) {
#pragma unroll
            for (int i = 0; i < 16; ++i) {
                if ((i & dd) == 0) {
                    float lo = fminf(m[i], m[i | dd]);
                    m[i | dd] = fmaxf(m[i], m[i | dd]);
                    m[i] = lo;
                }
            }
        }
        float t = -__builtin_huge_valf();
#pragma unroll
        for (int i = 0; i < 16; ++i)
            t = fmaxf(t, fminf(m[i], __shfl_xor(m[15 - i], 2, 64)));
        return t;
    };

#define DIST_(c)                                                            \
    float dx = __fsub_rn(qx, (c).x);                                        \
    float dy = __fsub_rn(qy, (c).y);                                        \
    float dz = __fsub_rn(qz, (c).z);                                        \
    float d  = __fadd_rn(__fadd_rn(__fmul_rn(dx,dx), __fmul_rn(dy,dy)),     \
                         __fmul_rn(dz,dz));

#define SCAN_P1(base, cntT) {                                               \
    __syncthreads();                                                        \
    if (tid < (cntT)) tile[tid] = pos4s[(base) + tid];                      \
    __syncthreads();                                                        \
    float g_ = fminf(bd15, sbd);                                            \
    _Pragma("unroll 4")                                                     \
    for (int j = sub; j < (cntT); j += 4) {                                 \
        float4 c = tile[j];                                                 \
        DIST_(c)                                                            \
        if (d < g_) {                                                       \
            _Pragma("unroll")                                               \
            for (int t = K_-1; t > 0; --t)                                  \
                bd[t] = fminf(bd[t], fmaxf(bd[t-1], d));                    \
            bd[0] = fminf(bd[0], d);                                        \
            bd15 = bd[K_-1];                                                \
            g_ = fminf(bd15, sbd);                                          \
        }                                                                   \
    } }

    // ---- pass 1: home tile, then center-outward expansion ----
    SCAN_P1(home0, 256)
    int sL = home0, sR = home0 + 256;
    for (;;) {
        sbd = QUAD16();                               // exact union 16th
        bool needL = false, needR = false;
        if (sL > bbase) {
            float xb = xl[bucket_of(pos4s[sL - 1].x)];   // ub on x of slots < sL
            float t = __fsub_rn(qx, xb);
            needL = __fmul_rn(t, t) < sbd;
        }
        if (sR < bbase + P_) {
            float xb = xg[bucket_of(pos4s[sR].x)];       // lb on x of slots >= sR
            float t = __fsub_rn(xb, qx);
            needR = __fmul_rn(t, t) < sbd;
        }
        if (tid == 0) { sflags[0] = 0; sflags[1] = 0; }
        __syncthreads();
        if (needL) sflags[0] = 1;
        if (needR) sflags[1] = 1;
        __syncthreads();
        int aL = sflags[0], aR = sflags[1];
        if (!aL && !aR) break;
        if (aL) { int c_ = min(256, sL - bbase);       SCAN_P1(sL - c_, c_) sL -= c_; }
        if (aR) { int c_ = min(256, bbase + P_ - sR);  SCAN_P1(sR, c_)      sR += c_; }
    }

    // ---- pass 2: collect (d, idx) with d <= tau (tau exact -> >=16 hits) ----
    const float tau = QUAD16();
    int cnt = 0;
    const int hbase = tid * 19;

#define SCAN_P2(base, cntT) {                                               \
    __syncthreads();                                                        \
    if (tid < (cntT)) tile[tid] = pos4s[(base) + tid];                      \
    __syncthreads();                                                        \
    _Pragma("unroll 4")                                                     \
    for (int j = sub; j < (cntT); j += 4) {                                 \
        float4 c = tile[j];                                                 \
        DIST_(c)                                                            \
        if (d <= tau && cnt < 19) {                                         \
            hbD[hbase + cnt] = d;                                           \
            hbI[hbase + cnt] = (unsigned short)__float_as_int(c.w);         \
            ++cnt;                                                          \
        }                                                                   \
    } }

    SCAN_P2(home0, 256)
    sL = home0; sR = home0 + 256;
    for (;;) {
        bool needL = false, needR = false;
        if (sL > bbase) {
            float xb = xl[bucket_of(pos4s[sL - 1].x)];
            float t = __fsub_rn(qx, xb);
            needL = __fmul_rn(t, t) <= tau;
        }
        if (sR < bbase + P_) {
            float xb = xg[bucket_of(pos4s[sR].x)];
            float t = __fsub_rn(xb, qx);
            needR = __fmul_rn(t, t) <= tau;
        }
        if (tid == 0) { sflags[0] = 0; sflags[1] = 0; }
        __syncthreads();
        if (needL) sflags[0] = 1;
        if (needR) sflags[1] = 1;
        __syncthreads();
        int aL = sflags[0], aR = sflags[1];
        if (!aL && !aR) break;
        if (aL) { int c_ = min(256, sL - bbase);       SCAN_P2(sL - c_, c_) sL -= c_; }
        if (aR) { int c_ = min(256, bbase + P_ - sR);  SCAN_P2(sR, c_)      sR += c_; }
    }

    // ---- distributed tie-drop (lex-largest) + scatter write ----
    // quad-uniform loop: counts travel by shuffle; each thread touches only
    // its own LDS hit region, so no barriers are needed here.
    const int qb = (tid & 63) & ~3;                  // quad base lane
    for (;;) {
        int c0 = __shfl(cnt, qb + 0, 64);
        int c1 = __shfl(cnt, qb + 1, 64);
        int c2 = __shfl(cnt, qb + 2, 64);
        int c3 = __shfl(cnt, qb + 3, 64);
        int total = c0 + c1 + c2 + c3;
        if (total <= 16) {
            int prefix = (sub > 0 ? c0 : 0) + (sub > 1 ? c1 : 0) + (sub > 2 ? c2 : 0);
            for (int t = 0; t < cnt; ++t) {
                size_t o = (size_t)q * K_ + prefix + t;
                idx_out[o] = hbI[hbase + t];
                d2_out[o]  = hbD[hbase + t];
            }
            break;
        }
        // local lex-max (d, idx)
        float md = -1.f; int mi = -1; int mt = -1;
        for (int t = 0; t < cnt; ++t) {
            float dt = hbD[hbase + t]; int it = (int)hbI[hbase + t];
            if (dt > md || (dt == md && it > mi)) { md = dt; mi = it; mt = t; }
        }
        // quad lex-max via packed key (d >= 0 so float bit order == uint order)
        unsigned long long key = cnt
            ? ((((unsigned long long)__float_as_uint(md)) << 17) | (unsigned)(mi + 1))
            : 0ull;
        unsigned long long kq = key;
        { unsigned long long o1 = (unsigned long long)__shfl_xor((long long)kq, 1, 64); if (o1 > kq) kq = o1; }
        { unsigned long long o2 = (unsigned long long)__shfl_xor((long long)kq, 2, 64); if (o2 > kq) kq = o2; }
        if (key == kq && cnt > 0) {                  // unique owner (indices unique)
            hbD[hbase + mt] = hbD[hbase + cnt - 1];
            hbI[hbase + mt] = hbI[hbase + cnt - 1];
            --cnt;
        }
    }
#undef SCAN_P1
#undef SCAN_P2
#undef DIST_
}

// ============================ edgeconv (barrier-free) ======================
// A group (the COUT lanes handling one point) lives entirely inside ONE wave
// (COUT=64: group == wave; COUT=32: half-wave). All LDS producer->consumer
// handoffs are wave-internal: per-wave LDS program order + compiler lgkmcnt
// waits make them correct with only __builtin_amdgcn_wave_barrier() (a
// zero-cost compiler fence) -- no s_barrier in the whole main loop.
// COUT=64 Kv/Qv partials combine via shfl_xor(16) (no LDS round-trip).
// Phase A: f32 per-point partial sums (16 bounded terms), folded to f64 once
// per point (f64 cancellation safety across the 1M-sample reduction).
template<int CIN, int COUT, bool PHA>
__global__ __launch_bounds__(256) void edge_kernel(
    const float* __restrict__ x,
    const unsigned short* __restrict__ idx,
    const float* __restrict__ d2,
    const float* __restrict__ W,
    const float* __restrict__ bias,
    const float* __restrict__ wk,
    const float* __restrict__ wq,
    const float* __restrict__ acoef,
    const float* __restrict__ ccoef,
    double* __restrict__ gsum,
    double* __restrict__ gsumsq,
    float* __restrict__ out,
    int niter)
{
    constexpr int LOGC = (COUT == 64) ? 6 : 5;
    constexpr int GPW  = 64 / COUT;
    constexpr int GPB  = 4 * GPW;
    constexpr int C4   = CIN / 4;
    constexpr int SJ   = (K_ + 1) * CIN;
    constexpr int HTS  = COUT + 1;
    constexpr int HTN  = PHA ? 1 : (K_ * HTS);
    constexpr int PN   = PHA ? 1 : (K_ * K_);
    constexpr int KQN  = PHA ? 1 : (2 * K_);
    constexpr int SCN  = PHA ? 1 : K_;
    constexpr int WKQN = PHA ? 1 : (2 * COUT);

    const int tid  = threadIdx.x;
    const int wave = tid >> 6;
    const int lane = tid & 63;
    const int lo   = lane & (COUT - 1);
    const int grp  = lane >> LOGC;
    const int gidx = wave * GPW + grp;

    __shared__ __align__(16) float sj_s[GPB][SJ];
    __shared__ __align__(16) float hT_s[GPB][HTN];
    __shared__ __align__(16) float p_s[GPB][PN];
    __shared__ __align__(16) float kqv_s[GPB][KQN];
    __shared__ __align__(16) float rden_s[GPB][SCN];
    __shared__ __align__(16) float scal_s[GPB][SCN];
    __shared__ __align__(16) float wkq_s[WKQN];

    float Wr[CIN], Ad[CIN];
#pragma unroll
    for (int c = 0; c < CIN; ++c) {
        float wl = W[lo * (2*CIN) + c];
        float wr = W[lo * (2*CIN) + CIN + c];
        Wr[c] = wr; Ad[c] = wl - wr;
    }
    const float b_s = bias[lo];

    float a_s = 0.f, c_s = 0.f;
    if constexpr (!PHA) {
        a_s = acoef[lo]; c_s = ccoef[lo];
        if (tid < COUT)            wkq_s[tid] = wk[tid];
        else if (tid < 2*COUT)     wkq_s[tid] = wq[tid - COUT];
        __syncthreads();   // the ONLY block barrier (wkq_s is cross-wave)
    }

    double lsum = 0.0, lsq = 0.0;
    const int g0      = blockIdx.x * GPB + gidx;
    const int gstride = gridDim.x * GPB;

    for (int it = 0; it < niter; ++it) {
        const int n = g0 + it * gstride;

        // ---- stage xj rows (k<K) and xi row (k==K) into LDS (float4) ----
        {
            const float4* xs  = (const float4*)x;
            float4*       sj4 = (float4*)sj_s[gidx];
            constexpr int TOT4 = (K_ + 1) * C4;
#pragma unroll
            for (int e0 = 0; e0 < TOT4; e0 += COUT) {
                int e = e0 + lo;
                if (e < TOT4) {
                    int r = e / C4;
                    int c = e - r * C4;
                    int row = (r < K_) ? (int)idx[n * K_ + r] : n;
                    sj4[e] = xs[row * C4 + c];
                }
            }
        }
        if constexpr (!PHA) {
            if (lo < K_) {
                float dis = sqrtf(d2[n * K_ + lo]);
                float e = __expf(-dis);
                scal_s[gidx][lo] = 2.0f * e / (1.0f + e);
            }
        }
        __builtin_amdgcn_wave_barrier();   // staging -> compute (wave-internal)

        const float* sj = sj_s[gidx];
        float t0 = b_s;
#pragma unroll
        for (int c = 0; c < C4; ++c) {
            float4 v = ((const float4*)(sj + K_ * CIN))[c];
            t0 = fmaf(Ad[4*c  ], v.x, t0);
            t0 = fmaf(Ad[4*c+1], v.y, t0);
            t0 = fmaf(Ad[4*c+2], v.z, t0);
            t0 = fmaf(Ad[4*c+3], v.w, t0);
        }
        float hn[K_];
        float psum = 0.f, psq = 0.f;
#pragma unroll
        for (int k = 0; k < K_; ++k) {
            float acc = t0;
            const float4* xr = (const float4*)(sj + k * CIN);
#pragma unroll
            for (int c = 0; c < C4; ++c) {
                float4 v = xr[c];
                acc = fmaf(Wr[4*c  ], v.x, acc);
                acc = fmaf(Wr[4*c+1], v.y, acc);
                acc = fmaf(Wr[4*c+2], v.z, acc);
                acc = fmaf(Wr[4*c+3], v.w, acc);
            }
            float h = fmaxf(acc, 0.f);
            if constexpr (PHA) {
                psum += h; psq = fmaf(h, h, psq);
            } else {
                hn[k] = fmaf(a_s, h, c_s);
            }
        }
        if constexpr (PHA) {
            lsum += (double)psum;        // f64 only across points
            lsq  += (double)psq;
        }

        if constexpr (!PHA) {
            // transpose to LDS (padded stride -> conflict-free columns)
            float* hT = hT_s[gidx];
#pragma unroll
            for (int k = 0; k < K_; ++k) hT[k * HTS + lo] = hn[k];
            __builtin_amdgcn_wave_barrier();   // transpose -> Kv/Qv

            const int kk   = lo & 15;
            const int role = lo >> 4;
            float av = 0.f;
            const float* hrow = hT + kk * HTS;
            int obase; const float* wv;
            if constexpr (COUT == 64) { obase = (role & 1) * 32; wv = wkq_s + ((role >> 1) ? COUT : 0); }
            else                      { obase = 0;               wv = wkq_s + (role ? COUT : 0); }
#pragma unroll
            for (int j = 0; j < 32; ++j)
                av = fmaf(hrow[obase + j], wv[obase + j], av);
            if constexpr (COUT == 64) {
                // halves combine in-register: lanes {kk,kk+16}->Kv, {kk+32,kk+48}->Qv
                float sum2 = av + __shfl_xor(av, 16, 64);
                if (lo < 16)                  kqv_s[gidx][kk] = sum2;        // Kv
                else if (lo >= 32 && lo < 48) kqv_s[gidx][16 + kk] = sum2;   // Qv
            } else {
                kqv_s[gidx][lo] = av;   // [0,16)=Kv, [16,32)=Qv
            }
            __builtin_amdgcn_wave_barrier();   // kqv -> softmax

            if (lo < K_) {
                const int qq = lo;
                const float qv = kqv_s[gidx][K_ + qq];
                float m = -__builtin_huge_valf();
#pragma unroll
                for (int k = 0; k < K_; ++k) m = fmaxf(m, kqv_s[gidx][k] * qv);
                float den = 0.f;
#pragma unroll
                for (int k = 0; k < K_; ++k) {
                    float e = __expf(kqv_s[gidx][k] * qv - m);
                    den += e;
                    p_s[gidx][k * K_ + qq] = e;
                }
                rden_s[gidx][qq] = 1.0f / den;
            }
            __builtin_amdgcn_wave_barrier();   // softmax -> weighted sum

            float hq[K_];
#pragma unroll
            for (int qq = 0; qq < K_; ++qq) hq[qq] = 0.f;
#pragma unroll
            for (int k = 0; k < K_; ++k) {
                const float hnk = hn[k];
                const float4* p4 = (const float4*)(p_s[gidx] + k * K_);
#pragma unroll
                for (int j = 0; j < 4; ++j) {
                    float4 v = p4[j];
                    hq[4*j  ] = fmaf(hnk, v.x, hq[4*j  ]);
                    hq[4*j+1] = fmaf(hnk, v.y, hq[4*j+1]);
                    hq[4*j+2] = fmaf(hnk, v.z, hq[4*j+2]);
                    hq[4*j+3] = fmaf(hnk, v.w, hq[4*j+3]);
                }
            }
            float res = -__builtin_huge_valf();
#pragma unroll
            for (int j = 0; j < 4; ++j) {
                float4 sc = ((const float4*)scal_s[gidx])[j];
                float4 rd = ((const float4*)rden_s[gidx])[j];
                res = fmaxf(res, sc.x * (hq[4*j  ] * rd.x));
                res = fmaxf(res, sc.y * (hq[4*j+1] * rd.y));
                res = fmaxf(res, sc.z * (hq[4*j+2] * rd.z));
                res = fmaxf(res, sc.w * (hq[4*j+3] * rd.w));
            }
            out[n * COUT + lo] = res;
            __builtin_amdgcn_wave_barrier();   // epilogue -> next-iter staging
        } else {
            __builtin_amdgcn_wave_barrier();   // compute -> next-iter staging
        }
    }

    if constexpr (PHA) {
        if constexpr (COUT == 32) {
            // fold the two half-wave groups (shuffle across lane 32 boundary)
            long long bs = __double_as_longlong(lsum);
            int l0 = __shfl_xor((int)(bs & 0xffffffffLL), 32, 64);
            int h0 = __shfl_xor((int)(bs >> 32), 32, 64);
            lsum += __longlong_as_double(((long long)h0 << 32) | (unsigned long long)(unsigned int)l0);
            bs = __double_as_longlong(lsq);
            l0 = __shfl_xor((int)(bs & 0xffffffffLL), 32, 64);
            h0 = __shfl_xor((int)(bs >> 32), 32, 64);
            lsq += __longlong_as_double(((long long)h0 << 32) | (unsigned long long)(unsigned int)l0);
        }
        __shared__ double redS[4][COUT];
        __shared__ double redQ[4][COUT];
        if (lane < COUT) { redS[wave][lane] = lsum; redQ[wave][lane] = lsq; }
        __syncthreads();
        if (tid < COUT) {
            double ss = redS[0][tid] + redS[1][tid] + redS[2][tid] + redS[3][tid];
            double qq = redQ[0][tid] + redQ[1][tid] + redQ[2][tid] + redQ[3][tid];
            atomicAdd(&gsum[tid], ss);
            atomicAdd(&gsumsq[tid], qq);
        }
    }
}

__global__ void finalize_kernel(const double* __restrict__ gsum, const double* __restrict__ gsumsq,
                                const float* __restrict__ gamma, const float* __restrict__ beta,
                                float* __restrict__ a, float* __restrict__ c, int cout)
{
    int o = threadIdx.x;
    if (o < cout) {
        const double inv = 1.0 / ((double)N_ * (double)K_);
        double mu  = gsum[o] * inv;
        double var = gsumsq[o] * inv - mu * mu;
        double rs  = 1.0 / sqrt(var + (double)EPS_);
        double av  = rs * (double)gamma[o];
        a[o] = (float)av;
        c[o] = (float)((double)beta[o] - mu * av);
    }
}

__global__ __launch_bounds__(256) void copy_vc(const float4* __restrict__ src,
                                               float4* __restrict__ dst) {
    int i = blockIdx.x * 256 + threadIdx.x;
    dst[i] = src[i];
}

extern "C" void kernel_launch(void* const* d_in, const int* in_sizes, int n_in,
                              void* d_out, int out_size, void* d_ws, size_t ws_size,
                              hipStream_t stream)
{
    const float* pillar = (const float*)d_in[0];
    const float* vc     = (const float*)d_in[1];
    const float* W0  = (const float*)d_in[2];
    const float* b0  = (const float*)d_in[3];
    const float* g0  = (const float*)d_in[4];
    const float* be0 = (const float*)d_in[5];
    const float* wk0 = (const float*)d_in[6];
    const float* wq0 = (const float*)d_in[7];
    const float* W1  = (const float*)d_in[8];
    const float* b1  = (const float*)d_in[9];
    const float* g1  = (const float*)d_in[10];
    const float* be1 = (const float*)d_in[11];
    const float* wk1 = (const float*)d_in[12];
    const float* wq1 = (const float*)d_in[13];

    // ---- workspace (< 16 MiB total) ----
    char* ws = (char*)d_ws;
    double* dsum = (double*)ws;                              // 2 KB @ 0
    double *s0 = dsum, *sq0 = dsum + 64, *s1 = dsum + 128, *sq1 = dsum + 192;
    float* coef = (float*)(ws + 4096);                       // 1 KB @ 4K
    float *a0 = coef, *c0 = coef + 64, *a1 = coef + 128, *c1 = coef + 192;
    unsigned short* idx = (unsigned short*)(ws + 8192);      // 2 MB
    float* d2  = (float*)(ws + 8192 + (size_t)N_*K_*2);      // 4 MB
    float* x1  = (float*)(ws + 8192 + (size_t)N_*K_*6);      // 8 MB
    size_t base2 = 8192 + (size_t)N_*K_*6 + (size_t)N_*32*4; // = 14 MB + 8 KB
    float4* pos4s = (float4*)(ws + base2);                   // 1 MB
    int* counts   = (int*)(ws + base2 + (1u<<20));           // 32 KB
    int* cursors  = counts + B_*NBK;                         // 32 KB
    int* off      = cursors + B_*NBK;                        // 8*1025*4
    int* xminI    = off + B_*(NBK+1);                        // 32 KB
    int* xmaxI    = xminI + B_*NBK;                          // 32 KB
    float* xlub   = (float*)(xmaxI + B_*NBK);                // 32 KB
    float* xglb   = xlub + B_*NBK;                           // 32 KB

    float* xout = (float*)d_out;
    float* vout = xout + (size_t)N_ * 64;

    hipMemsetAsync(dsum, 0, 2048, stream);
    init_bins<<<B_*NBK/256, 256, 0, stream>>>(counts, cursors, xminI, xmaxI);
    count_kernel<<<N_/256, 256, 0, stream>>>(vc, counts, xminI, xmaxI);
    scan_kernel<<<B_, NBK, 0, stream>>>(counts, xminI, xmaxI, off, xlub, xglb);
    scatter_kernel<<<N_/256, 256, 0, stream>>>(vc, off, cursors, pos4s);
    knn3_kernel<<<N_/64, 256, 0, stream>>>(pos4s, xlub, xglb, idx, d2);

    edge_kernel<4,32,true ><<<1024, 256, 0, stream>>>(pillar, idx, d2, W0, b0, wk0, wq0,
                                                      nullptr, nullptr, s0, sq0, nullptr, 8);
    finalize_kernel<<<1, 64, 0, stream>>>(s0, sq0, g0, be0, a0, c0, 32);
    edge_kernel<4,32,false><<<1024, 256, 0, stream>>>(pillar, idx, d2, W0, b0, wk0, wq0,
                                                      a0, c0, nullptr, nullptr, x1, 8);

    edge_kernel<32,64,true ><<<2048, 256, 0, stream>>>(x1, idx, d2, W1, b1, wk1, wq1,
                                                       nullptr, nullptr, s1, sq1, nullptr, 8);
    finalize_kernel<<<1, 64, 0, stream>>>(s1, sq1, g1, be1, a1, c1, 64);
    edge_kernel<32,64,false><<<2048, 256, 0, stream>>>(x1, idx, d2, W1, b1, wk1, wq1,
                                                       a1, c1, nullptr, nullptr, xout, 8);

    copy_vc<<<256, 256, 0, stream>>>((const float4*)vc, (float4*)vout);
}

// Round 2
// 622.298 us; speedup vs baseline: 1.5218x; 1.0871x over previous
//
#include <hip/hip_runtime.h>
#include <math.h>

#define B_ 8
#define P_ 8192
#define N_ 65536
#define K_ 16
#define EPS_ 1e-5f
#define NBK 1024                 // x-buckets per batch
#define BSCALE 20.48f            // NBK / 50.0

// ============================ binning (R5, proven) =========================
__global__ __launch_bounds__(256) void init_bins(int* counts, int* cursors,
                                                 int* xminI, int* xmaxI) {
    int i = blockIdx.x * 256 + threadIdx.x;   // 8192 entries
    counts[i] = 0; cursors[i] = 0;
    xminI[i] = 0x7F7FFFFF;                    // non-neg floats: int order == float order
    xmaxI[i] = 0x80000000;
}

__device__ __forceinline__ int bucket_of(float x) {
    int b = (int)(x * BSCALE);
    return b > (NBK - 1) ? (NBK - 1) : (b < 0 ? 0 : b);
}

__global__ __launch_bounds__(256) void count_kernel(const float* __restrict__ vc,
                                                    int* counts, int* xminI, int* xmaxI) {
    int q = blockIdx.x * 256 + threadIdx.x;
    float4 p = ((const float4*)vc)[q];        // [batch, x, y, z]
    int b = q >> 13;
    int bk = bucket_of(p.y);
    int e = b * NBK + bk;
    atomicAdd(&counts[e], 1);
    int xb = __float_as_int(p.y);
    atomicMin(&xminI[e], xb);
    atomicMax(&xmaxI[e], xb);
}

__global__ __launch_bounds__(1024) void scan_kernel(const int* __restrict__ counts,
                                                    const int* __restrict__ xminI,
                                                    const int* __restrict__ xmaxI,
                                                    int* off, float* xlub, float* xglb) {
    __shared__ int   smi[NBK];
    __shared__ float smf[NBK];
    int b = blockIdx.x, t = threadIdx.x;
    int e = b * NBK + t;

    int c = counts[e];
    smi[t] = c; __syncthreads();
    for (int s = 1; s < NBK; s <<= 1) {
        int u = smi[t]; int v = (t >= s) ? smi[t - s] : 0;
        __syncthreads(); smi[t] = u + v; __syncthreads();
    }
    off[b * (NBK + 1) + t] = smi[t] - c;
    if (t == NBK - 1) off[b * (NBK + 1) + NBK] = smi[t];

    float mx = c ? __int_as_float(xmaxI[e]) : -1e30f;
    smf[t] = mx; __syncthreads();
    for (int s = 1; s < NBK; s <<= 1) {
        float u = smf[t]; float v = (t >= s) ? smf[t - s] : -1e30f;
        __syncthreads(); smf[t] = fmaxf(u, v); __syncthreads();
    }
    xlub[e] = smf[t];
    __syncthreads();

    int r = NBK - 1 - t;
    int cr_ = counts[b * NBK + r];
    float mn = cr_ ? __int_as_float(xminI[b * NBK + r]) : 1e30f;
    smf[t] = mn; __syncthreads();
    for (int s = 1; s < NBK; s <<= 1) {
        float u = smf[t]; float v = (t >= s) ? smf[t - s] : 1e30f;
        __syncthreads(); smf[t] = fminf(u, v); __syncthreads();
    }
    xglb[b * NBK + r] = smf[t];
}

__global__ __launch_bounds__(256) void scatter_kernel(const float* __restrict__ vc,
                                                      const int* __restrict__ off,
                                                      int* cursors, float4* pos4s) {
    int q = blockIdx.x * 256 + threadIdx.x;
    float4 p = ((const float4*)vc)[q];
    int b = q >> 13;
    int bk = bucket_of(p.y);
    int slot = off[b * (NBK + 1) + bk] + atomicAdd(&cursors[b * NBK + bk], 1);
    pos4s[(b << 13) + slot] = make_float4(p.y, p.z, p.w, __int_as_float(q));
}

// ============== knn5: single-pass exact top-k, packed f64 keys =============
// 4 threads/query quad (R1, proven). NEW: instead of pass1 (distances only) +
// pass2 (re-scan for indices) + LDS hit buffer + tie-drop, keep a sorted list
// of PACKED keys:  key = (f32bits(d) << 16) | q   bit-cast to f64.
//   - d >= 0  -> float bit order == unsigned order; q < 2^16; keys < 2^48
//     -> positive DENORMAL f64 (exponent field 0). f64 denormals are never
//     flushed on AMD, so v_min_f64/v_max_f64 give (d, idx)-lex order in ONE
//     instruction each. Keys are unique (unique q) -> no ties anywhere.
//   - insertion network + quad bitonic merges run on packed keys -> the
//     union top-16 carries indices with it; pass 2 deleted (~45% of work),
//     hit-buffer LDS deleted (33.8 KB -> 4.2 KB), tie semantics now EXACTLY
//     lax.top_k's (16 smallest d, smaller index wins ties).
//   - hot loop still compares float d vs float threshold; packed insertion
//     only on hit. Expansion bound uses <= (tie-inclusive, pass-2 semantics).
__global__ __launch_bounds__(256, 4) void knn3_kernel(const float4* __restrict__ pos4s,
                                                   const float* __restrict__ xlub,
                                                   const float* __restrict__ xglb,
                                                   unsigned short* __restrict__ idx_out,
                                                   float* __restrict__ d2_out) {
    const int tid   = threadIdx.x;
    const int sub   = tid & 3;                     // position within quad
    const int bb    = blockIdx.x >> 7;             // batch (128 blocks/batch)
    const int bbase = bb << 13;
    const int wq    = blockIdx.x & 127;            // 64-query group within batch
    const int home0 = bbase + ((wq >> 2) << 8);    // aligned 256-tile containing group
    const int qslot = bbase + (wq << 6) + (tid >> 2);
    const float4 me = pos4s[qslot];
    const float qx = me.x, qy = me.y, qz = me.z;
    const int q = __float_as_int(me.w);
    const float* xl = xlub + (bb << 10);
    const float* xg = xglb + (bb << 10);

    __shared__ __align__(16) float4 tile[256];       // 4 KB (total LDS now ~4.2 KB)
    __shared__ int sflags[2];

    const double KINF = __longlong_as_double(0x7F800000LL << 16);  // (inf, idx 0)
    double bd[16];
#pragma unroll
    for (int t = 0; t < 16; ++t) bd[t] = KINF;
    float bd15f = __builtin_huge_valf();             // own 16th distance
    float sbdf  = __builtin_huge_valf();             // quad-union 16th distance

    // 4-stage bitonic cleanup: sorts the bitonic lower-half of a merge.
    auto CLEAN16 = [](double* m) {
#pragma unroll
        for (int dd = 8; dd >= 1; dd >>= 1)
#pragma unroll
            for (int i = 0; i < 16; ++i)
                if ((i & dd) == 0) {
                    double lo = fmin(m[i], m[i | dd]);
                    m[i | dd] = fmax(m[i], m[i | dd]);
                    m[i] = lo;
                }
    };

    // exact union-16th KEY across the quad (all 4 lanes compute same value)
    auto QUAD16K = [&]() -> double {
        double m[16];
#pragma unroll
        for (int i = 0; i < 16; ++i)
            m[i] = fmin(bd[i], __shfl_xor(bd[15 - i], 1, 64));
        CLEAN16(m);
        double t = 0.0;
#pragma unroll
        for (int i = 0; i < 16; ++i)
            t = fmax(t, fmin(m[i], __shfl_xor(m[15 - i], 2, 64)));
        return t;
    };

#define DIST_(c)                                                            \
    float dx = __fsub_rn(qx, (c).x);                                        \
    float dy = __fsub_rn(qy, (c).y);                                        \
    float dz = __fsub_rn(qz, (c).z);                                        \
    float d  = __fadd_rn(__fadd_rn(__fmul_rn(dx,dx), __fmul_rn(dy,dy)),     \
                         __fmul_rn(dz,dz));

#define SCAN_(base, cntT) {                                                 \
    __syncthreads();                                                        \
    if (tid < (cntT)) tile[tid] = pos4s[(base) + tid];                      \
    __syncthreads();                                                        \
    float g_ = fminf(bd15f, sbdf);                                          \
    _Pragma("unroll 4")                                                     \
    for (int j = sub; j < (cntT); j += 4) {                                 \
        float4 c = tile[j];                                                 \
        DIST_(c)                                                            \
        if (d <= g_) {                                                      \
            double key = __longlong_as_double(                              \
                ((long long)((unsigned long long)__float_as_uint(d) << 16)) \
                | (long long)(unsigned long long)((unsigned)__float_as_int(c.w) & 0xFFFFu)); \
            _Pragma("unroll")                                               \
            for (int t = 15; t > 0; --t)                                    \
                bd[t] = fmin(bd[t], fmax(bd[t-1], key));                    \
            bd[0] = fmin(bd[0], key);                                       \
            bd15f = __uint_as_float((unsigned)                              \
                ((unsigned long long)__double_as_longlong(bd[15]) >> 16));  \
            g_ = fminf(bd15f, sbdf);                                        \
        }                                                                   \
    } }

    // ---- home tile, then center-outward expansion (single pass) ----
    SCAN_(home0, 256)
    int sL = home0, sR = home0 + 256;
    for (;;) {
        double sk = QUAD16K();                        // exact union 16th key
        sbdf = __uint_as_float((unsigned)
            ((unsigned long long)__double_as_longlong(sk) >> 16));
        bool needL = false, needR = false;
        if (sL > bbase) {
            float xb = xl[bucket_of(pos4s[sL - 1].x)];   // ub on x of slots < sL
            float t = __fsub_rn(qx, xb);
            needL = __fmul_rn(t, t) <= sbdf;             // tie-inclusive
        }
        if (sR < bbase + P_) {
            float xb = xg[bucket_of(pos4s[sR].x)];       // lb on x of slots >= sR
            float t = __fsub_rn(xb, qx);
            needR = __fmul_rn(t, t) <= sbdf;
        }
        if (tid == 0) { sflags[0] = 0; sflags[1] = 0; }
        __syncthreads();
        if (needL) sflags[0] = 1;
        if (needR) sflags[1] = 1;
        __syncthreads();
        int aL = sflags[0], aR = sflags[1];
        if (!aL && !aR) break;
        if (aL) { int c_ = min(256, sL - bbase);       SCAN_(sL - c_, c_) sL -= c_; }
        if (aR) { int c_ = min(256, bbase + P_ - sR);  SCAN_(sR, c_)      sR += c_; }
    }

    // ---- full sorted union top-16 (all 4 quad lanes converge) ----
    double m[16];
#pragma unroll
    for (int i = 0; i < 16; ++i)
        m[i] = fmin(bd[i], __shfl_xor(bd[15 - i], 1, 64));
    CLEAN16(m);
    double u[16];
#pragma unroll
    for (int i = 0; i < 16; ++i)
        u[i] = fmin(m[i], __shfl_xor(m[15 - i], 2, 64));
    CLEAN16(u);

    // lane sub==0 of each quad writes its query's 16 results (vectorized,
    // statically indexed -> no scratch). Sorted ascending by (d, idx),
    // exactly lax.top_k order.
    if (sub == 0) {
        float4*  d4 = (float4*)(d2_out + (size_t)q * K_);
        ushort4* i4 = (ushort4*)(idx_out + (size_t)q * K_);
#define OUT4(t4, a, b, cc, dd_)                                             \
        { unsigned long long ka = (unsigned long long)__double_as_longlong(u[a]);  \
          unsigned long long kb = (unsigned long long)__double_as_longlong(u[b]);  \
          unsigned long long kc = (unsigned long long)__double_as_longlong(u[cc]); \
          unsigned long long kd = (unsigned long long)__double_as_longlong(u[dd_]);\
          d4[t4] = make_float4(__uint_as_float((unsigned)(ka >> 16)),       \
                               __uint_as_float((unsigned)(kb >> 16)),       \
                               __uint_as_float((unsigned)(kc >> 16)),       \
                               __uint_as_float((unsigned)(kd >> 16)));      \
          i4[t4] = make_ushort4((unsigned short)(ka & 0xFFFFu),             \
                                (unsigned short)(kb & 0xFFFFu),             \
                                (unsigned short)(kc & 0xFFFFu),             \
                                (unsigned short)(kd & 0xFFFFu)); }
        OUT4(0, 0, 1, 2, 3)
        OUT4(1, 4, 5, 6, 7)
        OUT4(2, 8, 9, 10, 11)
        OUT4(3, 12, 13, 14, 15)
#undef OUT4
    }
#undef SCAN_
#undef DIST_
}

// ============================ edgeconv (barrier-free) ======================
// A group (the COUT lanes handling one point) lives entirely inside ONE wave
// (COUT=64: group == wave; COUT=32: half-wave). All LDS producer->consumer
// handoffs are wave-internal: per-wave LDS program order + compiler lgkmcnt
// waits make them correct with only __builtin_amdgcn_wave_barrier() (a
// zero-cost compiler fence) -- no s_barrier in the whole main loop.
// COUT=64 Kv/Qv partials combine via shfl_xor(16) (no LDS round-trip).
// Phase A: f32 per-point partial sums (16 bounded terms), folded to f64 once
// per point (f64 cancellation safety across the 1M-sample reduction).
template<int CIN, int COUT, bool PHA>
__global__ __launch_bounds__(256) void edge_kernel(
    const float* __restrict__ x,
    const unsigned short* __restrict__ idx,
    const float* __restrict__ d2,
    const float* __restrict__ W,
    const float* __restrict__ bias,
    const float* __restrict__ wk,
    const float* __restrict__ wq,
    const float* __restrict__ acoef,
    const float* __restrict__ ccoef,
    double* __restrict__ gsum,
    double* __restrict__ gsumsq,
    float* __restrict__ out,
    int niter)
{
    constexpr int LOGC = (COUT == 64) ? 6 : 5;
    constexpr int GPW  = 64 / COUT;
    constexpr int GPB  = 4 * GPW;
    constexpr int C4   = CIN / 4;
    constexpr int SJ   = (K_ + 1) * CIN;
    constexpr int HTS  = COUT + 1;
    constexpr int HTN  = PHA ? 1 : (K_ * HTS);
    constexpr int PN   = PHA ? 1 : (K_ * K_);
    constexpr int KQN  = PHA ? 1 : (2 * K_);
    constexpr int SCN  = PHA ? 1 : K_;
    constexpr int WKQN = PHA ? 1 : (2 * COUT);

    const int tid  = threadIdx.x;
    const int wave = tid >> 6;
    const int lane = tid & 63;
    const int lo   = lane & (COUT - 1);
    const int grp  = lane >> LOGC;
    const int gidx = wave * GPW + grp;

    __shared__ __align__(16) float sj_s[GPB][SJ];
    __shared__ __align__(16) float hT_s[GPB][HTN];
    __shared__ __align__(16) float p_s[GPB][PN];
    __shared__ __align__(16) float kqv_s[GPB][KQN];
    __shared__ __align__(16) float rden_s[GPB][SCN];
    __shared__ __align__(16) float scal_s[GPB][SCN];
    __shared__ __align__(16) float wkq_s[WKQN];

    float Wr[CIN], Ad[CIN];
#pragma unroll
    for (int c = 0; c < CIN; ++c) {
        float wl = W[lo * (2*CIN) + c];
        float wr = W[lo * (2*CIN) + CIN + c];
        Wr[c] = wr; Ad[c] = wl - wr;
    }
    const float b_s = bias[lo];

    float a_s = 0.f, c_s = 0.f;
    if constexpr (!PHA) {
        a_s = acoef[lo]; c_s = ccoef[lo];
        if (tid < COUT)            wkq_s[tid] = wk[tid];
        else if (tid < 2*COUT)     wkq_s[tid] = wq[tid - COUT];
        __syncthreads();   // the ONLY block barrier (wkq_s is cross-wave)
    }

    double lsum = 0.0, lsq = 0.0;
    const int g0      = blockIdx.x * GPB + gidx;
    const int gstride = gridDim.x * GPB;

    for (int it = 0; it < niter; ++it) {
        const int n = g0 + it * gstride;

        // ---- stage xj rows (k<K) and xi row (k==K) into LDS (float4) ----
        {
            const float4* xs  = (const float4*)x;
            float4*       sj4 = (float4*)sj_s[gidx];
            constexpr int TOT4 = (K_ + 1) * C4;
#pragma unroll
            for (int e0 = 0; e0 < TOT4; e0 += COUT) {
                int e = e0 + lo;
                if (e < TOT4) {
                    int r = e / C4;
                    int c = e - r * C4;
                    int row = (r < K_) ? (int)idx[n * K_ + r] : n;
                    sj4[e] = xs[row * C4 + c];
                }
            }
        }
        if constexpr (!PHA) {
            if (lo < K_) {
                float dis = sqrtf(d2[n * K_ + lo]);
                float e = __expf(-dis);
                scal_s[gidx][lo] = 2.0f * e / (1.0f + e);
            }
        }
        __builtin_amdgcn_wave_barrier();   // staging -> compute (wave-internal)

        const float* sj = sj_s[gidx];
        float t0 = b_s;
#pragma unroll
        for (int c = 0; c < C4; ++c) {
            float4 v = ((const float4*)(sj + K_ * CIN))[c];
            t0 = fmaf(Ad[4*c  ], v.x, t0);
            t0 = fmaf(Ad[4*c+1], v.y, t0);
            t0 = fmaf(Ad[4*c+2], v.z, t0);
            t0 = fmaf(Ad[4*c+3], v.w, t0);
        }
        float hn[K_];
        float psum = 0.f, psq = 0.f;
#pragma unroll
        for (int k = 0; k < K_; ++k) {
            float acc = t0;
            const float4* xr = (const float4*)(sj + k * CIN);
#pragma unroll
            for (int c = 0; c < C4; ++c) {
                float4 v = xr[c];
                acc = fmaf(Wr[4*c  ], v.x, acc);
                acc = fmaf(Wr[4*c+1], v.y, acc);
                acc = fmaf(Wr[4*c+2], v.z, acc);
                acc = fmaf(Wr[4*c+3], v.w, acc);
            }
            float h = fmaxf(acc, 0.f);
            if constexpr (PHA) {
                psum += h; psq = fmaf(h, h, psq);
            } else {
                hn[k] = fmaf(a_s, h, c_s);
            }
        }
        if constexpr (PHA) {
            lsum += (double)psum;        // f64 only across points
            lsq  += (double)psq;
        }

        if constexpr (!PHA) {
            // transpose to LDS (padded stride -> conflict-free columns)
            float* hT = hT_s[gidx];
#pragma unroll
            for (int k = 0; k < K_; ++k) hT[k * HTS + lo] = hn[k];
            __builtin_amdgcn_wave_barrier();   // transpose -> Kv/Qv

            const int kk   = lo & 15;
            const int role = lo >> 4;
            float av = 0.f;
            const float* hrow = hT + kk * HTS;
            int obase; const float* wv;
            if constexpr (COUT == 64) { obase = (role & 1) * 32; wv = wkq_s + ((role >> 1) ? COUT : 0); }
            else                      { obase = 0;               wv = wkq_s + (role ? COUT : 0); }
#pragma unroll
            for (int j = 0; j < 32; ++j)
                av = fmaf(hrow[obase + j], wv[obase + j], av);
            if constexpr (COUT == 64) {
                // halves combine in-register: lanes {kk,kk+16}->Kv, {kk+32,kk+48}->Qv
                float sum2 = av + __shfl_xor(av, 16, 64);
                if (lo < 16)                  kqv_s[gidx][kk] = sum2;        // Kv
                else if (lo >= 32 && lo < 48) kqv_s[gidx][16 + kk] = sum2;   // Qv
            } else {
                kqv_s[gidx][lo] = av;   // [0,16)=Kv, [16,32)=Qv
            }
            __builtin_amdgcn_wave_barrier();   // kqv -> softmax

            if (lo < K_) {
                const int qq = lo;
                const float qv = kqv_s[gidx][K_ + qq];
                float m = -__builtin_huge_valf();
#pragma unroll
                for (int k = 0; k < K_; ++k) m = fmaxf(m, kqv_s[gidx][k] * qv);
                float den = 0.f;
#pragma unroll
                for (int k = 0; k < K_; ++k) {
                    float e = __expf(kqv_s[gidx][k] * qv - m);
                    den += e;
                    p_s[gidx][k * K_ + qq] = e;
                }
                rden_s[gidx][qq] = 1.0f / den;
            }
            __builtin_amdgcn_wave_barrier();   // softmax -> weighted sum

            float hq[K_];
#pragma unroll
            for (int qq = 0; qq < K_; ++qq) hq[qq] = 0.f;
#pragma unroll
            for (int k = 0; k < K_; ++k) {
                const float hnk = hn[k];
                const float4* p4 = (const float4*)(p_s[gidx] + k * K_);
#pragma unroll
                for (int j = 0; j < 4; ++j) {
                    float4 v = p4[j];
                    hq[4*j  ] = fmaf(hnk, v.x, hq[4*j  ]);
                    hq[4*j+1] = fmaf(hnk, v.y, hq[4*j+1]);
                    hq[4*j+2] = fmaf(hnk, v.z, hq[4*j+2]);
                    hq[4*j+3] = fmaf(hnk, v.w, hq[4*j+3]);
                }
            }
            float res = -__builtin_huge_valf();
#pragma unroll
            for (int j = 0; j < 4; ++j) {
                float4 sc = ((const float4*)scal_s[gidx])[j];
                float4 rd = ((const float4*)rden_s[gidx])[j];
                res = fmaxf(res, sc.x * (hq[4*j  ] * rd.x));
                res = fmaxf(res, sc.y * (hq[4*j+1] * rd.y));
                res = fmaxf(res, sc.z * (hq[4*j+2] * rd.z));
                res = fmaxf(res, sc.w * (hq[4*j+3] * rd.w));
            }
            out[n * COUT + lo] = res;
            __builtin_amdgcn_wave_barrier();   // epilogue -> next-iter staging
        } else {
            __builtin_amdgcn_wave_barrier();   // compute -> next-iter staging
        }
    }

    if constexpr (PHA) {
        if constexpr (COUT == 32) {
            // fold the two half-wave groups (shuffle across lane 32 boundary)
            long long bs = __double_as_longlong(lsum);
            int l0 = __shfl_xor((int)(bs & 0xffffffffLL), 32, 64);
            int h0 = __shfl_xor((int)(bs >> 32), 32, 64);
            lsum += __longlong_as_double(((long long)h0 << 32) | (unsigned long long)(unsigned int)l0);
            bs = __double_as_longlong(lsq);
            l0 = __shfl_xor((int)(bs & 0xffffffffLL), 32, 64);
            h0 = __shfl_xor((int)(bs >> 32), 32, 64);
            lsq += __longlong_as_double(((long long)h0 << 32) | (unsigned long long)(unsigned int)l0);
        }
        __shared__ double redS[4][COUT];
        __shared__ double redQ[4][COUT];
        if (lane < COUT) { redS[wave][lane] = lsum; redQ[wave][lane] = lsq; }
        __syncthreads();
        if (tid < COUT) {
            double ss = redS[0][tid] + redS[1][tid] + redS[2][tid] + redS[3][tid];
            double qq = redQ[0][tid] + redQ[1][tid] + redQ[2][tid] + redQ[3][tid];
            atomicAdd(&gsum[tid], ss);
            atomicAdd(&gsumsq[tid], qq);
        }
    }
}

__global__ void finalize_kernel(const double* __restrict__ gsum, const double* __restrict__ gsumsq,
                                const float* __restrict__ gamma, const float* __restrict__ beta,
                                float* __restrict__ a, float* __restrict__ c, int cout)
{
    int o = threadIdx.x;
    if (o < cout) {
        const double inv = 1.0 / ((double)N_ * (double)K_);
        double mu  = gsum[o] * inv;
        double var = gsumsq[o] * inv - mu * mu;
        double rs  = 1.0 / sqrt(var + (double)EPS_);
        double av  = rs * (double)gamma[o];
        a[o] = (float)av;
        c[o] = (float)((double)beta[o] - mu * av);
    }
}

__global__ __launch_bounds__(256) void copy_vc(const float4* __restrict__ src,
                                               float4* __restrict__ dst) {
    int i = blockIdx.x * 256 + threadIdx.x;
    dst[i] = src[i];
}

extern "C" void kernel_launch(void* const* d_in, const int* in_sizes, int n_in,
                              void* d_out, int out_size, void* d_ws, size_t ws_size,
                              hipStream_t stream)
{
    const float* pillar = (const float*)d_in[0];
    const float* vc     = (const float*)d_in[1];
    const float* W0  = (const float*)d_in[2];
    const float* b0  = (const float*)d_in[3];
    const float* g0  = (const float*)d_in[4];
    const float* be0 = (const float*)d_in[5];
    const float* wk0 = (const float*)d_in[6];
    const float* wq0 = (const float*)d_in[7];
    const float* W1  = (const float*)d_in[8];
    const float* b1  = (const float*)d_in[9];
    const float* g1  = (const float*)d_in[10];
    const float* be1 = (const float*)d_in[11];
    const float* wk1 = (const float*)d_in[12];
    const float* wq1 = (const float*)d_in[13];

    // ---- workspace (< 16 MiB total) ----
    char* ws = (char*)d_ws;
    double* dsum = (double*)ws;                              // 2 KB @ 0
    double *s0 = dsum, *sq0 = dsum + 64, *s1 = dsum + 128, *sq1 = dsum + 192;
    float* coef = (float*)(ws + 4096);                       // 1 KB @ 4K
    float *a0 = coef, *c0 = coef + 64, *a1 = coef + 128, *c1 = coef + 192;
    unsigned short* idx = (unsigned short*)(ws + 8192);      // 2 MB
    float* d2  = (float*)(ws + 8192 + (size_t)N_*K_*2);      // 4 MB
    float* x1  = (float*)(ws + 8192 + (size_t)N_*K_*6);      // 8 MB
    size_t base2 = 8192 + (size_t)N_*K_*6 + (size_t)N_*32*4; // = 14 MB + 8 KB
    float4* pos4s = (float4*)(ws + base2);                   // 1 MB
    int* counts   = (int*)(ws + base2 + (1u<<20));           // 32 KB
    int* cursors  = counts + B_*NBK;                         // 32 KB
    int* off      = cursors + B_*NBK;                        // 8*1025*4
    int* xminI    = off + B_*(NBK+1);                        // 32 KB
    int* xmaxI    = xminI + B_*NBK;                          // 32 KB
    float* xlub   = (float*)(xmaxI + B_*NBK);                // 32 KB
    float* xglb   = xlub + B_*NBK;                           // 32 KB

    float* xout = (float*)d_out;
    float* vout = xout + (size_t)N_ * 64;

    hipMemsetAsync(dsum, 0, 2048, stream);
    init_bins<<<B_*NBK/256, 256, 0, stream>>>(counts, cursors, xminI, xmaxI);
    count_kernel<<<N_/256, 256, 0, stream>>>(vc, counts, xminI, xmaxI);
    scan_kernel<<<B_, NBK, 0, stream>>>(counts, xminI, xmaxI, off, xlub, xglb);
    scatter_kernel<<<N_/256, 256, 0, stream>>>(vc, off, cursors, pos4s);
    knn3_kernel<<<N_/64, 256, 0, stream>>>(pos4s, xlub, xglb, idx, d2);

    edge_kernel<4,32,true ><<<1024, 256, 0, stream>>>(pillar, idx, d2, W0, b0, wk0, wq0,
                                                      nullptr, nullptr, s0, sq0, nullptr, 8);
    finalize_kernel<<<1, 64, 0, stream>>>(s0, sq0, g0, be0, a0, c0, 32);
    edge_kernel<4,32,false><<<1024, 256, 0, stream>>>(pillar, idx, d2, W0, b0, wk0, wq0,
                                                      a0, c0, nullptr, nullptr, x1, 8);

    edge_kernel<32,64,true ><<<2048, 256, 0, stream>>>(x1, idx, d2, W1, b1, wk1, wq1,
                                                       nullptr, nullptr, s1, sq1, nullptr, 8);
    finalize_kernel<<<1, 64, 0, stream>>>(s1, sq1, g1, be1, a1, c1, 64);
    edge_kernel<32,64,false><<<2048, 256, 0, stream>>>(x1, idx, d2, W1, b1, wk1, wq1,
                                                       a1, c1, nullptr, nullptr, xout, 8);

    copy_vc<<<256, 256, 0, stream>>>((const float4*)vc, (float4*)vout);
}